// Round 4
// baseline (1299.082 us; speedup 1.0000x reference)
//
#include <hip/hip_runtime.h>
#include <math.h>

#define P_TOTAL 147456
#define HW 9216
#define CHW (512*9216)
#define NBR 128

__device__ __forceinline__ unsigned f2key(float f) {
    unsigned u = __float_as_uint(f);
    return (u & 0x80000000u) ? ~u : (u | 0x80000000u);
}

__device__ __forceinline__ float agload(const float* p) {
    return __hip_atomic_load(p, __ATOMIC_RELAXED, __HIP_MEMORY_SCOPE_AGENT);
}
__device__ __forceinline__ void agstoref(float* p, float v) {
    __hip_atomic_store(p, v, __ATOMIC_RELAXED, __HIP_MEMORY_SCOPE_AGENT);
}

// ---------- K0: protoT [c][128] (j = side*64+k) and pworkT [side][c][64k] ----------
__global__ void k_init(const float* __restrict__ fg, const float* __restrict__ bg,
                       float* __restrict__ protoT, float* __restrict__ pworkT) {
    int i = blockIdx.x * 256 + threadIdx.x;   // 0..65535
    int side = i >> 15;
    int r = i & 32767;
    int k = r >> 9;
    int c = r & 511;
    float v = (side ? bg : fg)[k * 512 + c];
    protoT[c * 128 + side * 64 + k] = v;
    pworkT[side * 32768 + c * 64 + k] = v;
}

// ---------- K1: scoring GEMM + combine + hist1, fused ----------
// Grid 256 blocks (exactly 1/CU) x 512 thr (8 waves). Wave w owns j in [16w,16w+16).
// Each lane: 9 points (p0 + i*64), 16 clusters -> acc[16][9] = 144 regs.
// Per c-iter/wave: 9 global loads (ping-pong prefetch depth 2) + 4 LDS b128
// broadcasts + 144 FMAs -> LDS pipe demand ~0.22 instr/cyc (under cap), VALU-bound.
__global__ __launch_bounds__(512, 2) void k_score(const float* __restrict__ F,
                                                  const float* __restrict__ protoT,
                                                  const float* __restrict__ M,
                                                  float* __restrict__ sfg,
                                                  float* __restrict__ sbg,
                                                  float* __restrict__ invout,
                                                  unsigned* __restrict__ hist) {
    __shared__ float lds[8192];               // 32 KB proto chunk [c][128 j]
    const int t = threadIdx.x;
    const int lane = t & 63;
    const int w = t >> 6;                     // 0..7 ; j range [16w, 16w+16)
    const int p0 = blockIdx.x * 576 + lane;   // 9216 % 576 == 0 -> one image per block
    const int n = p0 / HW;
    const int hw0 = p0 - n * HW;
    const float* Fb = F + (size_t)n * CHW;

    float acc[16][9];
#pragma unroll
    for (int jj = 0; jj < 16; ++jj)
#pragma unroll
        for (int i = 0; i < 9; ++i) acc[jj][i] = 0.f;
    float nn[9];
#pragma unroll
    for (int i = 0; i < 9; ++i) nn[i] = 0.f;

    auto ldch = [&](float (&dst)[9], int ch) {
        int chc = ch > 511 ? 511 : ch;
        const float* q = Fb + hw0 + (size_t)chc * HW;
#pragma unroll
        for (int i = 0; i < 9; ++i) dst[i] = q[i * 64];
    };
    auto kstep = [&](const float (&f)[9], int cc) {
        const float4* pv4 = (const float4*)(lds + cc * 128 + w * 16);
#pragma unroll
        for (int j4 = 0; j4 < 4; ++j4) {
            float4 bq = pv4[j4];
#pragma unroll
            for (int i = 0; i < 9; ++i) {
                acc[j4 * 4 + 0][i] = fmaf(f[i], bq.x, acc[j4 * 4 + 0][i]);
                acc[j4 * 4 + 1][i] = fmaf(f[i], bq.y, acc[j4 * 4 + 1][i]);
                acc[j4 * 4 + 2][i] = fmaf(f[i], bq.z, acc[j4 * 4 + 2][i]);
                acc[j4 * 4 + 3][i] = fmaf(f[i], bq.w, acc[j4 * 4 + 3][i]);
            }
        }
    };

    float fa[9], fb[9];
    ldch(fa, 0); ldch(fb, 1);
    int ch = 2;

    for (int chunk = 0; chunk < 8; ++chunk) {
        __syncthreads();
        {
            const float4* src = (const float4*)(protoT + chunk * 8192);
            float4* dst = (float4*)lds;
#pragma unroll
            for (int i2 = 0; i2 < 4; ++i2) dst[t + 512 * i2] = src[t + 512 * i2];
        }
        __syncthreads();
        for (int c2 = 0; c2 < 32; ++c2) {
            if (w == 0) {
#pragma unroll
                for (int i = 0; i < 9; ++i) nn[i] = fmaf(fa[i], fa[i], nn[i]);
            }
            kstep(fa, c2 * 2);
            ldch(fa, ch++);
            if (w == 0) {
#pragma unroll
                for (int i = 0; i < 9; ++i) nn[i] = fmaf(fb[i], fb[i], nn[i]);
            }
            kstep(fb, c2 * 2 + 1);
            ldch(fb, ch++);
        }
    }

    // per-thread max over its 16 clusters
    float m16[9];
#pragma unroll
    for (int i = 0; i < 9; ++i) {
        float mm = acc[0][i];
#pragma unroll
        for (int jj = 1; jj < 16; ++jj) mm = fmaxf(mm, acc[jj][i]);
        m16[i] = mm;
    }
    __syncthreads();
#pragma unroll
    for (int i = 0; i < 9; ++i) lds[w * 576 + i * 64 + lane] = m16[i];
    if (w == 0) {
#pragma unroll
        for (int i = 0; i < 9; ++i) lds[4608 + i * 64 + lane] = nn[i];
    }
    __syncthreads();
    for (int pi = t; pi < 576; pi += 512) {
        int p = blockIdx.x * 576 + pi;
        float fgm = fmaxf(fmaxf(lds[pi], lds[576 + pi]), fmaxf(lds[1152 + pi], lds[1728 + pi]));
        float bgm = fmaxf(fmaxf(lds[2304 + pi], lds[2880 + pi]), fmaxf(lds[3456 + pi], lds[4032 + pi]));
        float inv = 1.f / fmaxf(sqrtf(lds[4608 + pi]), 1e-8f);
        float mm = fminf(fmaxf(M[p], 0.f), 1.f);
        float sf = (1.f - fgm * inv) * mm;
        float sb = (1.f - bgm * inv) * (1.f - mm);
        sfg[p] = sf; sbg[p] = sb; invout[p] = inv;
        atomicAdd(&hist[f2key(sf) >> 16], 1u);
        atomicAdd(&hist[65536 + (f2key(sb) >> 16)], 1u);
    }
}

// ---------- scan: find threshold bucket (pass 0) / exact key (pass 1) ----------
__global__ __launch_bounds__(1024) void k_scan(const unsigned* __restrict__ hist,
                                               int* __restrict__ ctrl, int pass) {
    __shared__ unsigned sd[1024];
    int side = blockIdx.x;
    const unsigned* h = hist + side * 65536;
    int t = threadIdx.x;
    unsigned partial = 0;
    for (int j = 0; j < 64; ++j) partial += h[65535 - (t * 64 + j)];
    sd[t] = partial;
    __syncthreads();
    for (int off = 1; off < 1024; off <<= 1) {
        unsigned v = (t >= off) ? sd[t - off] : 0u;
        __syncthreads();
        sd[t] += v;
        __syncthreads();
    }
    unsigned incl = sd[t];
    unsigned excl = incl - partial;
    unsigned target = (pass == 0) ? 256u : (unsigned)ctrl[side * 8 + 1];
    if (excl < target && target <= incl) {
        unsigned cum = excl;
        for (int j = 0; j < 64; ++j) {
            int b = 65535 - (t * 64 + j);
            unsigned c = h[b];
            if (cum + c >= target) {
                if (pass == 0) {
                    ctrl[side * 8 + 0] = b;
                    ctrl[side * 8 + 1] = (int)(target - cum);
                } else {
                    unsigned vkey = ((unsigned)ctrl[side * 8 + 0] << 16) | (unsigned)b;
                    ctrl[side * 8 + 2] = (int)vkey;
                    int n_gt = (int)(256u - (unsigned)ctrl[side * 8 + 1] + cum);
                    ctrl[side * 8 + 3] = n_gt;
                    ctrl[side * 8 + 4] = 256 - n_gt;
                }
                break;
            }
            cum += c;
        }
    }
}

__global__ void k_hist2(const float* __restrict__ sfg, const float* __restrict__ sbg,
                        const int* __restrict__ ctrl, unsigned* __restrict__ hist2) {
    int side = blockIdx.y;
    int p = blockIdx.x * 256 + threadIdx.x;
    float s = side ? sbg[p] : sfg[p];
    unsigned key = f2key(s);
    if ((int)(key >> 16) == ctrl[side * 8 + 0])
        atomicAdd(&hist2[side * 65536 + (key & 0xffffu)], 1u);
}

__global__ void k_collect(const float* __restrict__ sfg, const float* __restrict__ sbg,
                          int* __restrict__ ctrl, int* __restrict__ idx, int* __restrict__ ties) {
    int side = blockIdx.y;
    int p = blockIdx.x * 256 + threadIdx.x;
    float s = side ? sbg[p] : sfg[p];
    unsigned key = f2key(s);
    unsigned vkey = (unsigned)ctrl[side * 8 + 2];
    if (key > vkey) {
        int pos = atomicAdd(&ctrl[side * 8 + 5], 1);
        idx[side * 256 + pos] = p;
    } else if (key == vkey) {
        int pos = atomicAdd(&ctrl[side * 8 + 6], 1);
        if (pos < 512) ties[side * 512 + pos] = p;
    }
}

__global__ void k_finalize(int* __restrict__ ctrl, int* __restrict__ idx, int* __restrict__ ties) {
    int side = threadIdx.x;
    if (side >= 2) return;
    int n_gt = ctrl[side * 8 + 3];
    int need = ctrl[side * 8 + 4];
    int cnt = ctrl[side * 8 + 6];
    if (cnt > 512) cnt = 512;
    int* tb = ties + side * 512;
    for (int q = 0; q < need; ++q) {
        int mi = q;
        for (int j = q + 1; j < cnt; ++j) if (tb[j] < tb[mi]) mi = j;
        int tmp = tb[q]; tb[q] = tb[mi]; tb[mi] = tmp;
        idx[side * 256 + n_gt + q] = tb[q];
    }
}

__global__ void k_gather(const float* __restrict__ F, const float* __restrict__ inv,
                         const int* __restrict__ idx, float* __restrict__ feats) {
    int b = blockIdx.x;              // 0..511
    int side = b >> 8, j = b & 255;
    int p = idx[side * 256 + j];
    float iv = inv[p];
    int n = p / HW, hw = p - n * HW;
    const float* Fp = F + (size_t)n * CHW + hw;
    float* o = feats + (size_t)(side * 256 + j) * 512;
    for (int c = threadIdx.x; c < 512; c += 256)
        o[c] = Fp[(size_t)c * HW] * iv;
}

// ---------- fused refine (10 iters) + losspart + final + refined ----------
// Grid 128 x 256 thr, 64 KB LDS -> all blocks co-resident (guaranteed).
// Cross-block data (pworkT, sums, counts, lpart) via agent-scope atomics
// (coherent point) because per-XCD L2s are not coherent. Grid barrier:
// monotonic-epoch atomic counter.
__global__ __launch_bounds__(256) void k_refine(const float* __restrict__ feats,
                                                float* __restrict__ pworkT,
                                                float* __restrict__ sums,
                                                float* __restrict__ counts,
                                                const float* __restrict__ fg,
                                                const float* __restrict__ bg,
                                                float* __restrict__ lpart,
                                                float* __restrict__ out,
                                                int* __restrict__ bar) {
    __shared__ float lds[16384];     // 64 KB: one half-side [256 c][64 k]
    const int t = threadIdx.x;
    const int lane = t & 63;
    const int w = t >> 6;
    const int blk = blockIdx.x;
    const int side = blk >> 6;       // rows' side AND this block's cluster side
    const int kk = blk & 63;         // this block's cluster
    const int row = blk * 4 + w;     // 0..511
    const int j = row & 255;
    const float4* fr4 = (const float4*)(feats + (size_t)row * 512);
    const float* frf = feats + (size_t)row * 512;

    auto gbar = [&](int e) {
        __syncthreads();
        __threadfence();
        if (t == 0) {
            atomicAdd(bar, 1);
            while (__hip_atomic_load(bar, __ATOMIC_RELAXED, __HIP_MEMORY_SCOPE_AGENT) < e * NBR)
                __builtin_amdgcn_s_sleep(2);
        }
        __syncthreads();
        __threadfence();
    };
    auto stage = [&](int s, int h) {  // copy pworkT[s], channels [h*256,h*256+256) -> lds (identity)
        const float* src = pworkT + (size_t)s * 32768 + (size_t)h * 16384;
        float4* d = (float4*)lds;
#pragma unroll
        for (int q = 0; q < 16; ++q) {
            int e4 = t + 256 * q;
            const float* s4 = src + (size_t)e4 * 4;
            float x0 = agload(s4), x1 = agload(s4 + 1), x2 = agload(s4 + 2), x3 = agload(s4 + 3);
            d[e4] = make_float4(x0, x1, x2, x3);
        }
    };
    auto dot_half = [&](int h) -> float {   // lane = cluster; accumulate c ascending
        float d = 0.f;
#pragma unroll 8
        for (int c4 = 0; c4 < 64; ++c4) {
            float4 a = fr4[h * 64 + c4];
            int base = c4 * 256 + lane;
            d = fmaf(a.x, lds[base], d);
            d = fmaf(a.y, lds[base + 64], d);
            d = fmaf(a.z, lds[base + 128], d);
            d = fmaf(a.w, lds[base + 192], d);
        }
        return d;
    };

    int ep = 0;
    for (int it = 0; it < 10; ++it) {
        // ---- assign ----
        stage(side, 0);
        __syncthreads();
        float dot = dot_half(0);
        __syncthreads();
        stage(side, 1);
        __syncthreads();
        dot += dot_half(1);

        float bv = dot; int bi = lane;
#pragma unroll
        for (int m = 32; m >= 1; m >>= 1) {
            float ov = __shfl_xor(bv, m);
            int oi = __shfl_xor(bi, m);
            if (ov > bv || (ov == bv && oi < bi)) { bv = ov; bi = oi; }
        }
        if (lane == 0) atomicAdd(&counts[side * 64 + bi], 1.f);
        float* srow = sums + (size_t)side * 32768 + (size_t)bi * 512;
#pragma unroll
        for (int i = 0; i < 8; ++i) {
            int c = lane + i * 64;
            atomicAdd(&srow[c], frf[c]);
        }
        gbar(++ep);

        // ---- update (this block's cluster kk) ----
        if (t < 64) {
            float cnt = agload(&counts[side * 64 + kk]);
            float* srow2 = sums + (size_t)side * 32768 + (size_t)kk * 512;
            float* pw = pworkT + (size_t)side * 32768;
            float step = (float)(0.1 / (1.0 + 0.5 * (double)it));
            float bl[8]; float n2 = 0.f;
#pragma unroll
            for (int i = 0; i < 8; ++i) {
                int c = t + i * 64;
                float s = agload(&srow2[c]);
                float mean = s / fmaxf(cnt, 1.f);
                float pv = agload(&pw[(size_t)c * 64 + kk]);
                float v = (1.f - step) * pv + step * mean;
                bl[i] = v; n2 = fmaf(v, v, n2);
                agstoref(&srow2[c], 0.f);
            }
#pragma unroll
            for (int m = 32; m >= 1; m >>= 1) n2 += __shfl_xor(n2, m);
            float inv = 1.f / fmaxf(sqrtf(n2), 1e-8f);
            if (cnt > 0.f) {
#pragma unroll
                for (int i = 0; i < 8; ++i) {
                    int c = t + i * 64;
                    agstoref(&pw[(size_t)c * 64 + kk], bl[i] * inv);
                }
            }
            if (t == 0) agstoref(&counts[side * 64 + kk], 0.f);
        }
        gbar(++ep);
    }

    // ---- refined protos (this block's cluster) ----
    if (t < 64) {
        const float* proto = (side ? bg : fg) + (size_t)kk * 512;
        const float* pw = pworkT + (size_t)side * 32768;
        float bl[8]; float n2 = 0.f;
#pragma unroll
        for (int i = 0; i < 8; ++i) {
            int c = t + i * 64;
            float v = 0.7f * proto[c] + 0.3f * agload(&pw[(size_t)c * 64 + kk]);
            bl[i] = v; n2 = fmaf(v, v, n2);
        }
#pragma unroll
        for (int m = 32; m >= 1; m >>= 1) n2 += __shfl_xor(n2, m);
        float inv = 1.f / fmaxf(sqrtf(n2), 1e-8f);
#pragma unroll
        for (int i = 0; i < 8; ++i)
            out[1 + side * 32768 + kk * 512 + t + i * 64] = bl[i] * inv;
    }

    // ---- loss partials ----
    stage(0, 0);
    __syncthreads();
    float d1 = dot_half(0);
    __syncthreads();
    stage(0, 1);
    __syncthreads();
    d1 += dot_half(1);
    float d2 = 0.f;
    if (side == 0) {
        __syncthreads();
        stage(1, 0);
        __syncthreads();
        d2 = dot_half(0);
        __syncthreads();
        stage(1, 1);
        __syncthreads();
        d2 += dot_half(1);
    }
    if (side == 0) {
        float smax = d1;
        for (int m = 32; m >= 1; m >>= 1) smax = fmaxf(smax, __shfl_xor(smax, m));
        float a = d1 / 0.07f, b = d2 / 0.07f;
        float m1 = a;
        for (int m = 32; m >= 1; m >>= 1) m1 = fmaxf(m1, __shfl_xor(m1, m));
        float mb = b;
        for (int m = 32; m >= 1; m >>= 1) mb = fmaxf(mb, __shfl_xor(mb, m));
        float md = fmaxf(m1, mb);
        float sn = expf(a - m1);
        for (int m = 32; m >= 1; m >>= 1) sn += __shfl_xor(sn, m);
        float sdn = expf(a - md) + expf(b - md);
        for (int m = 32; m >= 1; m >>= 1) sdn += __shfl_xor(sdn, m);
        float num = m1 + logf(sn);
        float den = md + logf(sdn);
        if (lane == 0) { agstoref(&lpart[j], smax); agstoref(&lpart[512 + j], num - den); }
    } else {
        float smax = d1;
        for (int m = 32; m >= 1; m >>= 1) smax = fmaxf(smax, __shfl_xor(smax, m));
        if (lane == 0) agstoref(&lpart[256 + j], smax);
    }
    gbar(++ep);

    // ---- final scalar loss (block 0) ----
    if (blk == 0) {
        float sp = agload(&lpart[t]), sn = agload(&lpart[256 + t]), nm = agload(&lpart[512 + t]);
#pragma unroll
        for (int m = 32; m >= 1; m >>= 1) {
            sp += __shfl_xor(sp, m); sn += __shfl_xor(sn, m); nm += __shfl_xor(nm, m);
        }
        if ((t & 63) == 0) { lds[w] = sp; lds[8 + w] = sn; lds[16 + w] = nm; }
        __syncthreads();
        if (t == 0) {
            float SP = 0, SN = 0, NM = 0;
            for (int i = 0; i < 4; ++i) { SP += lds[i]; SN += lds[8 + i]; NM += lds[16 + i]; }
            SP /= 256.f; SN /= 256.f; NM /= 256.f;
            out[0] = fmaxf(0.f, 0.2f + SN - SP) + 0.25f * (-NM);
        }
    }
}

extern "C" void kernel_launch(void* const* d_in, const int* in_sizes, int n_in,
                              void* d_out, int out_size, void* d_ws, size_t ws_size,
                              hipStream_t stream) {
    const float* fg = (const float*)d_in[0];
    const float* bg = (const float*)d_in[1];
    const float* F  = (const float*)d_in[2];
    const float* M  = (const float*)d_in[3];
    float* out = (float*)d_out;
    char* ws = (char*)d_ws;

    size_t o = 0;
    auto alloc = [&](size_t bytes) { size_t r = o; o += (bytes + 1023) & ~(size_t)1023; return r; };
    // zero region
    size_t off_hist1 = alloc(2 * 65536 * 4);
    size_t off_hist2 = alloc(2 * 65536 * 4);
    size_t off_ctrl  = alloc(64);
    size_t off_cnts  = alloc(2 * 64 * 4);
    size_t off_sums  = alloc(2 * 64 * 512 * 4);
    size_t off_bar   = alloc(64);
    size_t zbytes = o;
    size_t off_sfg   = alloc(P_TOTAL * 4);
    size_t off_sbg   = alloc(P_TOTAL * 4);
    size_t off_inv   = alloc(P_TOTAL * 4);
    size_t off_pT    = alloc(512 * 128 * 4);
    size_t off_idx   = alloc(2 * 256 * 4);
    size_t off_ties  = alloc(2 * 512 * 4);
    size_t off_feats = alloc(2 * 256 * 512 * 4);
    size_t off_pwork = alloc(2 * 64 * 512 * 4);
    size_t off_lpart = alloc(768 * 4);

    unsigned* hist1 = (unsigned*)(ws + off_hist1);
    unsigned* hist2 = (unsigned*)(ws + off_hist2);
    int* ctrl   = (int*)(ws + off_ctrl);
    float* cnts = (float*)(ws + off_cnts);
    float* sums = (float*)(ws + off_sums);
    int* bar    = (int*)(ws + off_bar);
    float* sfg  = (float*)(ws + off_sfg);
    float* sbg  = (float*)(ws + off_sbg);
    float* inv  = (float*)(ws + off_inv);
    float* pT   = (float*)(ws + off_pT);
    int* idx    = (int*)(ws + off_idx);
    int* ties   = (int*)(ws + off_ties);
    float* feats = (float*)(ws + off_feats);
    float* pworkT = (float*)(ws + off_pwork);
    float* lpart = (float*)(ws + off_lpart);

    hipMemsetAsync(ws, 0, zbytes, stream);
    k_init<<<256, 256, 0, stream>>>(fg, bg, pT, pworkT);
    k_score<<<256, 512, 0, stream>>>(F, pT, M, sfg, sbg, inv, hist1);
    k_scan<<<2, 1024, 0, stream>>>(hist1, ctrl, 0);
    k_hist2<<<dim3(576, 2), 256, 0, stream>>>(sfg, sbg, ctrl, hist2);
    k_scan<<<2, 1024, 0, stream>>>(hist2, ctrl, 1);
    k_collect<<<dim3(576, 2), 256, 0, stream>>>(sfg, sbg, ctrl, idx, ties);
    k_finalize<<<1, 64, 0, stream>>>(ctrl, idx, ties);
    k_gather<<<512, 256, 0, stream>>>(F, inv, idx, feats);
    k_refine<<<128, 256, 0, stream>>>(feats, pworkT, sums, cnts, fg, bg, lpart, out, bar);
}